// Round 2
// baseline (1320.448 us; speedup 1.0000x reference)
//
#include <hip/hip_runtime.h>
#include <math.h>

#define NSAMP 131072
#define HID 64

__device__ __forceinline__ float fast_tanh(float x) {
    float ax = fabsf(x);
    float e = __builtin_amdgcn_exp2f(ax * 2.88539008177793f); // exp(2|x|)
    float r = 1.0f - 2.0f * __builtin_amdgcn_rcpf(e + 1.0f);
    return copysignf(r, x);
}

__global__ __launch_bounds__(256, 1)
void cnf_logp_kernel(const float* __restrict__ xin, const float* __restrict__ tin,
                     const float* __restrict__ W1, const float* __restrict__ b1,
                     const float* __restrict__ W2, const float* __restrict__ b2,
                     const float* __restrict__ W3, const float* __restrict__ b3,
                     const float* __restrict__ vol, float* __restrict__ out)
{
    // Wave-uniform weight tables in LDS (all reads broadcast, conflict-free).
    __shared__ float4 sW1t[HID];        // (W1[0][k], W1[1][k], W1[2][k], W1[3][k])
    __shared__ float  sb1[HID];
    __shared__ float4 sWH[HID * 16 * 2];// [(k*16+j4)*2+0]=W2 quad, +1 = H quad
    __shared__ float4 sb2v[16];
    __shared__ float4 scs4[16];         // colsum_j = sum_k H[k][j], packed by j4
    __shared__ float4 sW3v[HID];        // (W3[j][0..2], 0)
    __shared__ float  sb3[4];

    const int tid = threadIdx.x;

    for (int i = tid; i < HID; i += 256) {
        sW1t[i] = make_float4(W1[0*64 + i], W1[1*64 + i], W1[2*64 + i], W1[3*64 + i]);
        sb1[i]  = b1[i];
        sW3v[i] = make_float4(W3[i*3 + 0], W3[i*3 + 1], W3[i*3 + 2], 0.0f);
    }
    // W2 / H quads: i enumerates (k, j4)
    for (int i = tid; i < HID * 16; i += 256) {
        int k = i >> 4, j4 = i & 15;
        float4 w2q, hq;
        float w1k0 = W1[0*64 + k], w1k1 = W1[1*64 + k], w1k2 = W1[2*64 + k];
        {
            int j = j4*4 + 0; float w2 = W2[k*64 + j];
            float g = w1k0*W3[j*3+0] + w1k1*W3[j*3+1] + w1k2*W3[j*3+2];
            w2q.x = w2; hq.x = w2 * g;
        }
        {
            int j = j4*4 + 1; float w2 = W2[k*64 + j];
            float g = w1k0*W3[j*3+0] + w1k1*W3[j*3+1] + w1k2*W3[j*3+2];
            w2q.y = w2; hq.y = w2 * g;
        }
        {
            int j = j4*4 + 2; float w2 = W2[k*64 + j];
            float g = w1k0*W3[j*3+0] + w1k1*W3[j*3+1] + w1k2*W3[j*3+2];
            w2q.z = w2; hq.z = w2 * g;
        }
        {
            int j = j4*4 + 3; float w2 = W2[k*64 + j];
            float g = w1k0*W3[j*3+0] + w1k1*W3[j*3+1] + w1k2*W3[j*3+2];
            w2q.w = w2; hq.w = w2 * g;
        }
        sWH[i*2 + 0] = w2q;
        sWH[i*2 + 1] = hq;
    }
    if (tid < 16) sb2v[tid] = make_float4(b2[tid*4+0], b2[tid*4+1], b2[tid*4+2], b2[tid*4+3]);
    if (tid < 4)  sb3[tid]  = (tid < 3) ? b3[tid] : 0.0f;
    __syncthreads();
    if (tid < HID) {  // colsum over H
        const float* whf = (const float*)sWH;
        int j4 = tid >> 2, jc = tid & 3;
        float cs = 0.0f;
        for (int k = 0; k < HID; ++k) cs += whf[((k*16 + j4)*2 + 1)*4 + jc];
        ((float*)scs4)[tid] = cs;
    }
    __syncthreads();

    // Two samples per thread: grid = NSAMP/512 blocks of 256 threads.
    const int ia = blockIdx.x * 512 + tid;
    const int ib = ia + 256;

    const float xa0 = xin[ia*3+0], xa1 = xin[ia*3+1], xa2 = xin[ia*3+2];
    const float xb0 = xin[ib*3+0], xb1 = xin[ib*3+1], xb2 = xin[ib*3+2];
    const float ta = tin[ia], tb = tin[ib];

    float za0 = xa0, za1 = xa1, za2 = xa2;
    float zb0 = xb0, zb1 = xb1, zb2 = xb2;
    float dacca = 0.0f, daccb = 0.0f;
    const float hstep = 0.25f;
    float kza0=0.f,kza1=0.f,kza2=0.f, kzb0=0.f,kzb1=0.f,kzb2=0.f;
    float saa0=0.f,saa1=0.f,saa2=0.f, sab0=0.f,sab1=0.f,sab2=0.f;

    float h1a[HID], q1a[HID], h1b[HID], q1b[HID];

    #pragma unroll 1
    for (int it = 0; it < 16; ++it) {
        const int st   = it & 3;
        const int step = it >> 2;
        const float alpha = (st == 0) ? 0.0f : ((st == 3) ? hstep : 0.5f * hstep);
        const float wgt   = (st == 1 || st == 2) ? (hstep * (1.0f/3.0f)) : (hstep * (1.0f/6.0f));
        const float s     = (float)step * hstep + alpha;
        const float oms   = 1.0f - s;
        const float zia0 = fmaf(alpha, kza0, za0), zia1 = fmaf(alpha, kza1, za1), zia2 = fmaf(alpha, kza2, za2);
        const float zib0 = fmaf(alpha, kzb0, zb0), zib1 = fmaf(alpha, kzb1, zb1), zib2 = fmaf(alpha, kzb2, zb2);
        const float tta = ta * oms, ttb = tb * oms;

        // ---- layer 1 for both samples ----
        #pragma unroll
        for (int k = 0; k < HID; ++k) {
            float4 w1 = sW1t[k];
            float bk = sb1[k];
            float pa = fmaf(zia0, w1.x, fmaf(zia1, w1.y, fmaf(zia2, w1.z, fmaf(tta, w1.w, bk))));
            float pb = fmaf(zib0, w1.x, fmaf(zib1, w1.y, fmaf(zib2, w1.z, fmaf(ttb, w1.w, bk))));
            float ha = fast_tanh(pa), hb = fast_tanh(pb);
            h1a[k] = ha; q1a[k] = ha * ha;
            h1b[k] = hb; q1b[k] = hb * hb;
        }

        // ---- layer 2 + divergence bilinear + layer 3 ----
        float f0a = sb3[0], f1a = sb3[1], f2a = sb3[2], dva = 0.0f;
        float f0b = f0a,    f1b = f1a,    f2b = f2a,    dvb = 0.0f;
        #pragma unroll 1
        for (int j4 = 0; j4 < 16; ++j4) {
            float4 bb = sb2v[j4];
            float4 cs = scs4[j4];
            float a0a=bb.x,a1a=bb.y,a2a=bb.z,a3a=bb.w;
            float a0b=bb.x,a1b=bb.y,a2b=bb.z,a3b=bb.w;
            float d0a=0.f,d1a=0.f,d2a=0.f,d3a=0.f;
            float d0b=0.f,d1b=0.f,d2b=0.f,d3b=0.f;
            const float4* base = &sWH[j4*2];
            #pragma unroll
            for (int k = 0; k < HID; ++k) {
                float4 w2 = base[k*32 + 0];
                float4 hh = base[k*32 + 1];
                float hka = h1a[k], qka = q1a[k];
                float hkb = h1b[k], qkb = q1b[k];
                a0a = fmaf(hka, w2.x, a0a); a1a = fmaf(hka, w2.y, a1a);
                a2a = fmaf(hka, w2.z, a2a); a3a = fmaf(hka, w2.w, a3a);
                d0a = fmaf(qka, hh.x, d0a); d1a = fmaf(qka, hh.y, d1a);
                d2a = fmaf(qka, hh.z, d2a); d3a = fmaf(qka, hh.w, d3a);
                a0b = fmaf(hkb, w2.x, a0b); a1b = fmaf(hkb, w2.y, a1b);
                a2b = fmaf(hkb, w2.z, a2b); a3b = fmaf(hkb, w2.w, a3b);
                d0b = fmaf(qkb, hh.x, d0b); d1b = fmaf(qkb, hh.y, d1b);
                d2b = fmaf(qkb, hh.z, d2b); d3b = fmaf(qkb, hh.w, d3b);
            }
            float hv, sv; float4 w3;
            // j = j4*4 + 0
            w3 = sW3v[j4*4 + 0];
            hv = fast_tanh(a0a); sv = 1.0f - hv*hv;
            f0a = fmaf(hv, w3.x, f0a); f1a = fmaf(hv, w3.y, f1a); f2a = fmaf(hv, w3.z, f2a);
            dva = fmaf(sv, cs.x - d0a, dva);
            hv = fast_tanh(a0b); sv = 1.0f - hv*hv;
            f0b = fmaf(hv, w3.x, f0b); f1b = fmaf(hv, w3.y, f1b); f2b = fmaf(hv, w3.z, f2b);
            dvb = fmaf(sv, cs.x - d0b, dvb);
            // j = j4*4 + 1
            w3 = sW3v[j4*4 + 1];
            hv = fast_tanh(a1a); sv = 1.0f - hv*hv;
            f0a = fmaf(hv, w3.x, f0a); f1a = fmaf(hv, w3.y, f1a); f2a = fmaf(hv, w3.z, f2a);
            dva = fmaf(sv, cs.y - d1a, dva);
            hv = fast_tanh(a1b); sv = 1.0f - hv*hv;
            f0b = fmaf(hv, w3.x, f0b); f1b = fmaf(hv, w3.y, f1b); f2b = fmaf(hv, w3.z, f2b);
            dvb = fmaf(sv, cs.y - d1b, dvb);
            // j = j4*4 + 2
            w3 = sW3v[j4*4 + 2];
            hv = fast_tanh(a2a); sv = 1.0f - hv*hv;
            f0a = fmaf(hv, w3.x, f0a); f1a = fmaf(hv, w3.y, f1a); f2a = fmaf(hv, w3.z, f2a);
            dva = fmaf(sv, cs.z - d2a, dva);
            hv = fast_tanh(a2b); sv = 1.0f - hv*hv;
            f0b = fmaf(hv, w3.x, f0b); f1b = fmaf(hv, w3.y, f1b); f2b = fmaf(hv, w3.z, f2b);
            dvb = fmaf(sv, cs.z - d2b, dvb);
            // j = j4*4 + 3
            w3 = sW3v[j4*4 + 3];
            hv = fast_tanh(a3a); sv = 1.0f - hv*hv;
            f0a = fmaf(hv, w3.x, f0a); f1a = fmaf(hv, w3.y, f1a); f2a = fmaf(hv, w3.z, f2a);
            dva = fmaf(sv, cs.w - d3a, dva);
            hv = fast_tanh(a3b); sv = 1.0f - hv*hv;
            f0b = fmaf(hv, w3.x, f0b); f1b = fmaf(hv, w3.y, f1b); f2b = fmaf(hv, w3.z, f2b);
            dvb = fmaf(sv, cs.w - d3b, dvb);
        }

        // ---- stage update ----
        const float va0 = -ta * f0a, va1 = -ta * f1a, va2 = -ta * f2a, vda = ta * dva;
        const float vb0 = -tb * f0b, vb1 = -tb * f1b, vb2 = -tb * f2b, vdb = tb * dvb;
        kza0 = va0; kza1 = va1; kza2 = va2;
        kzb0 = vb0; kzb1 = vb1; kzb2 = vb2;
        dacca = fmaf(wgt, vda, dacca);
        daccb = fmaf(wgt, vdb, daccb);
        if (st == 0) {
            saa0 = wgt*va0; saa1 = wgt*va1; saa2 = wgt*va2;
            sab0 = wgt*vb0; sab1 = wgt*vb1; sab2 = wgt*vb2;
        } else {
            saa0 = fmaf(wgt, va0, saa0); saa1 = fmaf(wgt, va1, saa1); saa2 = fmaf(wgt, va2, saa2);
            sab0 = fmaf(wgt, vb0, sab0); sab1 = fmaf(wgt, vb1, sab1); sab2 = fmaf(wgt, vb2, sab2);
        }
        if (st == 3) {
            za0 += saa0; za1 += saa1; za2 += saa2;
            zb0 += sab0; zb1 += sab1; zb2 += sab2;
        }
    }

    // ---- epilogue: mask, grid-sample, logp (both samples) ----
    #pragma unroll
    for (int p = 0; p < 2; ++p) {
        const float t0 = p ? tb : ta;
        const bool m = (t0 > 0.0f);
        const float q0 = m ? (p ? zb0 : za0) : (p ? xb0 : xa0);
        const float q1 = m ? (p ? zb1 : za1) : (p ? xb1 : xa1);
        const float q2 = m ? (p ? zb2 : za2) : (p ? xb2 : xa2);
        const float dfin = m ? (p ? daccb : dacca) : 0.0f;

        const float px = ((q0 * 0.2f + 1.0f) * 100.0f - 1.0f) * 0.5f;
        const float py = ((q1 * 0.2f + 1.0f) * 100.0f - 1.0f) * 0.5f;
        const float pz = ((q2 * 0.2f + 1.0f) * 100.0f - 1.0f) * 0.5f;
        const float fx = floorf(px), fy = floorf(py), fz = floorf(pz);
        const int ix0 = (int)fx, iy0 = (int)fy, iz0 = (int)fz;
        const float wx1 = px - fx, wy1 = py - fy, wz1 = pz - fz;

        float gs = 0.0f;
        #pragma unroll
        for (int c = 0; c < 8; ++c) {
            const int dxc = c & 1, dyc = (c >> 1) & 1, dzc = (c >> 2) & 1;
            const int ix = ix0 + dxc, iy = iy0 + dyc, iz = iz0 + dzc;
            const float w = (dxc ? wx1 : 1.0f - wx1)
                          * (dyc ? wy1 : 1.0f - wy1)
                          * (dzc ? wz1 : 1.0f - wz1);
            if (ix >= 0 && ix < 100 && iy >= 0 && iy < 100 && iz >= 0 && iz < 100)
                gs += vol[(iz * 100 + iy) * 100 + ix] * w;
        }
        out[p ? ib : ia] = gs - dfin;
    }
}

extern "C" void kernel_launch(void* const* d_in, const int* in_sizes, int n_in,
                              void* d_out, int out_size, void* d_ws, size_t ws_size,
                              hipStream_t stream) {
    const float* x    = (const float*)d_in[0];
    const float* t    = (const float*)d_in[1];
    const float* W1   = (const float*)d_in[2];
    const float* b1   = (const float*)d_in[3];
    const float* W2   = (const float*)d_in[4];
    const float* b2   = (const float*)d_in[5];
    const float* W3   = (const float*)d_in[6];
    const float* b3   = (const float*)d_in[7];
    const float* vol  = (const float*)d_in[8];
    float* out = (float*)d_out;

    dim3 grid(NSAMP / 512), block(256);
    cnf_logp_kernel<<<grid, block, 0, stream>>>(x, t, W1, b1, W2, b2, W3, b3, vol, out);
}

// Round 3
// 220.736 us; speedup vs baseline: 5.9820x; 5.9820x over previous
//
#include <hip/hip_runtime.h>
#include <math.h>

#define NSAMP 131072

typedef _Float16 half8v __attribute__((ext_vector_type(8)));
typedef float    f32x4  __attribute__((ext_vector_type(4)));

__device__ __forceinline__ float fast_tanh(float x) {
    float ax = fabsf(x);
    float e = __builtin_amdgcn_exp2f(ax * 2.88539008177793f); // exp(2|x|)
    float r = 1.0f - 2.0f * __builtin_amdgcn_rcpf(e + 1.0f);
    return copysignf(r, x);
}

__global__ __launch_bounds__(256, 2)
void cnf_logp_kernel(const float* __restrict__ xin, const float* __restrict__ tin,
                     const float* __restrict__ W1, const float* __restrict__ b1,
                     const float* __restrict__ W2, const float* __restrict__ b2,
                     const float* __restrict__ W3, const float* __restrict__ b3,
                     const float* __restrict__ vol, float* __restrict__ out)
{
    __shared__ float4 sW1[64];   // (W1[0][k],W1[1][k],W1[2][k],W1[3][k])
    __shared__ float  sb1[64];

    const int tid = threadIdx.x;
    for (int i = tid; i < 64; i += 256) {
        sW1[i] = make_float4(W1[0*64 + i], W1[1*64 + i], W1[2*64 + i], W1[3*64 + i]);
        sb1[i] = b1[i];
    }
    __syncthreads();

    const int lane = tid & 63;
    const int col  = lane & 15;   // A-row / sample slot; also B/C column
    const int g    = lane >> 4;   // lane group

    // ---------------- build weight B-fragments (once) ----------------
    // k-map: k(e,g) = 4g + (e&3) + 16*(e>>2); global k = kh*32 + k(e,g).
    // Same map is used for A-frags -> any wiring mismatch cancels.
    half8v BW2[8];   // [nt*2+kh]
    half8v BH [8];
    float  w3x[4], w3y[4], w3z[4], b2j[4], cs[4];

    #pragma unroll
    for (int nt = 0; nt < 4; ++nt) {
        const int j = nt*16 + col;
        w3x[nt] = W3[j*3 + 0];
        w3y[nt] = W3[j*3 + 1];
        w3z[nt] = W3[j*3 + 2];
        b2j[nt] = b2[j];
    }
    #pragma unroll
    for (int nt = 0; nt < 4; ++nt) {
        const int j = nt*16 + col;
        float csacc = 0.0f;
        #pragma unroll
        for (int kh = 0; kh < 2; ++kh) {
            #pragma unroll
            for (int e = 0; e < 8; ++e) {
                const int kg = kh*32 + 4*g + (e & 3) + 16*(e >> 2);
                const float w2v = W2[kg*64 + j];
                const float gv  = W1[0*64 + kg]*w3x[nt]
                                + W1[1*64 + kg]*w3y[nt]
                                + W1[2*64 + kg]*w3z[nt];
                const _Float16 w2h = (_Float16)w2v;
                const _Float16 hh  = (_Float16)(w2v * gv);
                BW2[nt*2 + kh][e] = w2h;
                BH [nt*2 + kh][e] = hh;
                csacc += (float)hh;   // f16-consistent column sum
            }
        }
        // sum over the 4 lane-groups (this lane covered 16 of 64 k's)
        csacc += __shfl_xor(csacc, 16);
        csacc += __shfl_xor(csacc, 32);
        cs[nt] = csacc;
    }
    const float b3c0 = b3[0], b3c1 = b3[1], b3c2 = b3[2];

    // ---------------- per-sample state (sample = col, replicated x4) ----------------
    const int idx = blockIdx.x*64 + (tid >> 6)*16 + col;
    const float x0v = xin[idx*3 + 0], x1v = xin[idx*3 + 1], x2v = xin[idx*3 + 2];
    const float t0  = tin[idx];

    float z0 = x0v, z1 = x1v, z2 = x2v;
    float dacc = 0.0f;
    const float hstep = 0.25f;
    float kz0 = 0.f, kz1 = 0.f, kz2 = 0.f;
    float sa0 = 0.f, sa1 = 0.f, sa2 = 0.f;

    #pragma unroll 1
    for (int it = 0; it < 16; ++it) {
        const int st   = it & 3;
        const int step = it >> 2;
        const float alpha = (st == 0) ? 0.0f : ((st == 3) ? hstep : 0.5f * hstep);
        const float wgt   = (st == 1 || st == 2) ? (hstep * (1.0f/3.0f)) : (hstep * (1.0f/6.0f));
        const float s     = (float)step * hstep + alpha;
        const float zi0 = fmaf(alpha, kz0, z0);
        const float zi1 = fmaf(alpha, kz1, z1);
        const float zi2 = fmaf(alpha, kz2, z2);
        const float tt  = t0 * (1.0f - s);

        // ---- layer 1 -> A-fragments (h and h^2), same k-map as B ----
        half8v AH[2], AQ[2];
        #pragma unroll
        for (int kh = 0; kh < 2; ++kh) {
            #pragma unroll
            for (int e = 0; e < 8; ++e) {
                const int kg = kh*32 + 4*g + (e & 3) + 16*(e >> 2);
                const float4 w = sW1[kg];
                const float  bk = sb1[kg];
                const float pre = fmaf(zi0, w.x, fmaf(zi1, w.y, fmaf(zi2, w.z, fmaf(tt, w.w, bk))));
                const float h = fast_tanh(pre);
                AH[kh][e] = (_Float16)h;
                AQ[kh][e] = (_Float16)(h * h);
            }
        }

        // ---- layer 2 + divergence bilinear via MFMA ----
        f32x4 a2[4], d2[4];
        #pragma unroll
        for (int nt = 0; nt < 4; ++nt) {
            f32x4 ci; ci[0] = b2j[nt]; ci[1] = b2j[nt]; ci[2] = b2j[nt]; ci[3] = b2j[nt];
            f32x4 zi4; zi4[0] = 0.f; zi4[1] = 0.f; zi4[2] = 0.f; zi4[3] = 0.f;
            ci  = __builtin_amdgcn_mfma_f32_16x16x32_f16(AH[0], BW2[nt*2+0], ci, 0, 0, 0);
            ci  = __builtin_amdgcn_mfma_f32_16x16x32_f16(AH[1], BW2[nt*2+1], ci, 0, 0, 0);
            zi4 = __builtin_amdgcn_mfma_f32_16x16x32_f16(AQ[0], BH[nt*2+0], zi4, 0, 0, 0);
            zi4 = __builtin_amdgcn_mfma_f32_16x16x32_f16(AQ[1], BH[nt*2+1], zi4, 0, 0, 0);
            a2[nt] = ci; d2[nt] = zi4;
        }

        // ---- epilogue in C-layout: row = 4g + r, col j = nt*16 + col ----
        float pf0[4], pf1[4], pf2[4], pdv[4];
        #pragma unroll
        for (int r = 0; r < 4; ++r) { pf0[r] = b3c0; pf1[r] = b3c1; pf2[r] = b3c2; pdv[r] = 0.0f; }
        #pragma unroll
        for (int nt = 0; nt < 4; ++nt) {
            #pragma unroll
            for (int r = 0; r < 4; ++r) {
                const float h2 = fast_tanh(a2[nt][r]);
                const float s2 = 1.0f - h2*h2;
                pf0[r] = fmaf(h2, w3x[nt], pf0[r]);
                pf1[r] = fmaf(h2, w3y[nt], pf1[r]);
                pf2[r] = fmaf(h2, w3z[nt], pf2[r]);
                pdv[r] = fmaf(s2, cs[nt] - d2[nt][r], pdv[r]);
            }
        }
        // reduce over j: 16 lanes within the group hold distinct columns
        #pragma unroll
        for (int r = 0; r < 4; ++r) {
            pf0[r] += __shfl_xor(pf0[r], 1); pf0[r] += __shfl_xor(pf0[r], 2);
            pf0[r] += __shfl_xor(pf0[r], 4); pf0[r] += __shfl_xor(pf0[r], 8);
            pf1[r] += __shfl_xor(pf1[r], 1); pf1[r] += __shfl_xor(pf1[r], 2);
            pf1[r] += __shfl_xor(pf1[r], 4); pf1[r] += __shfl_xor(pf1[r], 8);
            pf2[r] += __shfl_xor(pf2[r], 1); pf2[r] += __shfl_xor(pf2[r], 2);
            pf2[r] += __shfl_xor(pf2[r], 4); pf2[r] += __shfl_xor(pf2[r], 8);
            pdv[r] += __shfl_xor(pdv[r], 1); pdv[r] += __shfl_xor(pdv[r], 2);
            pdv[r] += __shfl_xor(pdv[r], 4); pdv[r] += __shfl_xor(pdv[r], 8);
        }
        // redistribute to sample-major (sample s = col lives at group s>>2, reg s&3)
        const int rsel = lane & 3;
        float sf0 = pf0[0], sf1 = pf1[0], sf2 = pf2[0], sdv = pdv[0];
        sf0 = (rsel == 1) ? pf0[1] : sf0; sf0 = (rsel == 2) ? pf0[2] : sf0; sf0 = (rsel == 3) ? pf0[3] : sf0;
        sf1 = (rsel == 1) ? pf1[1] : sf1; sf1 = (rsel == 2) ? pf1[2] : sf1; sf1 = (rsel == 3) ? pf1[3] : sf1;
        sf2 = (rsel == 1) ? pf2[1] : sf2; sf2 = (rsel == 2) ? pf2[2] : sf2; sf2 = (rsel == 3) ? pf2[3] : sf2;
        sdv = (rsel == 1) ? pdv[1] : sdv; sdv = (rsel == 2) ? pdv[2] : sdv; sdv = (rsel == 3) ? pdv[3] : sdv;
        const int srcLane = ((col >> 2) << 4) | col;   // group col>>2, reg col&3
        const float f0 = __shfl(sf0, srcLane);
        const float f1 = __shfl(sf1, srcLane);
        const float f2 = __shfl(sf2, srcLane);
        const float dv = __shfl(sdv, srcLane);

        // ---- RK4 stage update (sample = col) ----
        const float v0 = -t0 * f0, v1 = -t0 * f1, v2 = -t0 * f2;
        const float vd =  t0 * dv;
        kz0 = v0; kz1 = v1; kz2 = v2;
        dacc = fmaf(wgt, vd, dacc);
        if (st == 0) { sa0 = wgt*v0; sa1 = wgt*v1; sa2 = wgt*v2; }
        else         { sa0 = fmaf(wgt, v0, sa0); sa1 = fmaf(wgt, v1, sa1); sa2 = fmaf(wgt, v2, sa2); }
        if (st == 3) { z0 += sa0; z1 += sa1; z2 += sa2; }
    }

    // ---------------- mask, grid-sample, store (group 0 only) ----------------
    if (g == 0) {
        const bool m = (t0 > 0.0f);
        const float q0 = m ? z0 : x0v;
        const float q1 = m ? z1 : x1v;
        const float q2 = m ? z2 : x2v;
        const float dfin = m ? dacc : 0.0f;

        const float px = ((q0 * 0.2f + 1.0f) * 100.0f - 1.0f) * 0.5f;
        const float py = ((q1 * 0.2f + 1.0f) * 100.0f - 1.0f) * 0.5f;
        const float pz = ((q2 * 0.2f + 1.0f) * 100.0f - 1.0f) * 0.5f;
        const float fx = floorf(px), fy = floorf(py), fz = floorf(pz);
        const int ix0 = (int)fx, iy0 = (int)fy, iz0 = (int)fz;
        const float wx1 = px - fx, wy1 = py - fy, wz1 = pz - fz;

        float gs = 0.0f;
        #pragma unroll
        for (int c = 0; c < 8; ++c) {
            const int dxc = c & 1, dyc = (c >> 1) & 1, dzc = (c >> 2) & 1;
            const int ix = ix0 + dxc, iy = iy0 + dyc, iz = iz0 + dzc;
            const float w = (dxc ? wx1 : 1.0f - wx1)
                          * (dyc ? wy1 : 1.0f - wy1)
                          * (dzc ? wz1 : 1.0f - wz1);
            if (ix >= 0 && ix < 100 && iy >= 0 && iy < 100 && iz >= 0 && iz < 100)
                gs += vol[(iz * 100 + iy) * 100 + ix] * w;
        }
        out[idx] = gs - dfin;
    }
}

extern "C" void kernel_launch(void* const* d_in, const int* in_sizes, int n_in,
                              void* d_out, int out_size, void* d_ws, size_t ws_size,
                              hipStream_t stream) {
    const float* x    = (const float*)d_in[0];
    const float* t    = (const float*)d_in[1];
    const float* W1   = (const float*)d_in[2];
    const float* b1   = (const float*)d_in[3];
    const float* W2   = (const float*)d_in[4];
    const float* b2   = (const float*)d_in[5];
    const float* W3   = (const float*)d_in[6];
    const float* b3   = (const float*)d_in[7];
    const float* vol  = (const float*)d_in[8];
    float* out = (float*)d_out;

    dim3 grid(NSAMP / 64), block(256);   // 4 waves/block, 16 samples/wave
    cnf_logp_kernel<<<grid, block, 0, stream>>>(x, t, W1, b1, W2, b2, W3, b3, vol, out);
}

// Round 4
// 116.777 us; speedup vs baseline: 11.3074x; 1.8902x over previous
//
#include <hip/hip_runtime.h>
#include <math.h>

#define NSAMP 131072

typedef _Float16 half8v __attribute__((ext_vector_type(8)));
typedef float    f32x4  __attribute__((ext_vector_type(4)));

__device__ __forceinline__ float fast_tanh(float x) {
    float ax = fabsf(x);
    float e = __builtin_amdgcn_exp2f(ax * 2.88539008177793f); // exp(2|x|)
    float r = 1.0f - 2.0f * __builtin_amdgcn_rcpf(e + 1.0f);
    return copysignf(r, x);
}

__global__ __launch_bounds__(256, 2)
void cnf_logp_kernel(const float* __restrict__ xin, const float* __restrict__ tin,
                     const float* __restrict__ W1, const float* __restrict__ b1,
                     const float* __restrict__ W2, const float* __restrict__ b2,
                     const float* __restrict__ W3, const float* __restrict__ b3,
                     const float* __restrict__ vol, float* __restrict__ out)
{
    __shared__ float4 sW1[64];   // (W1[0][k],W1[1][k],W1[2][k],W1[3][k])
    __shared__ float  sb1[64];

    const int tid = threadIdx.x;
    for (int i = tid; i < 64; i += 256) {
        sW1[i] = make_float4(W1[0*64 + i], W1[1*64 + i], W1[2*64 + i], W1[3*64 + i]);
        sb1[i] = b1[i];
    }
    __syncthreads();

    const int lane = tid & 63;
    const int col  = lane & 15;   // sample slot (B/C column); also A-row for weights
    const int g    = lane >> 4;   // lane group

    // ---------------- weight A-fragments (rows = j) ----------------
    // slot k-map (shared by ALL frags, so hw-map mismatches cancel):
    //   k(e,g) = 4g + (e&3) + 16*(e>>2), global k = kh*32 + k(e,g)
    half8v AW2[8];   // [nt*2+kh] : A[j = nt*16+col, k] = W2[k, j]
    half8v AHW[8];   // same for H[k,j] = W2[k,j] * sum_i W1[i,k] W3[j,i]
    float  cs_col[4];
    #pragma unroll
    for (int nt = 0; nt < 4; ++nt) {
        const int j = nt*16 + col;
        const float w3j0 = W3[j*3+0], w3j1 = W3[j*3+1], w3j2 = W3[j*3+2];
        float csacc = 0.0f;
        #pragma unroll
        for (int kh = 0; kh < 2; ++kh) {
            #pragma unroll
            for (int e = 0; e < 8; ++e) {
                const int k = kh*32 + 4*g + (e & 3) + 16*(e >> 2);
                const float w2v = W2[k*64 + j];
                const float gv  = W1[0*64+k]*w3j0 + W1[1*64+k]*w3j1 + W1[2*64+k]*w3j2;
                AW2[nt*2 + kh][e] = (_Float16)w2v;
                const _Float16 hh = (_Float16)(w2v * gv);
                AHW[nt*2 + kh][e] = hh;
                csacc += (float)hh;   // f16-consistent column sum of H
            }
        }
        csacc += __shfl_xor(csacc, 16);
        csacc += __shfl_xor(csacc, 32);
        cs_col[nt] = csacc;           // cs[j = nt*16+col], replicated over g
    }
    // redistribute cs/b2 to OUTPUT-j indexing: j_out = nt*16 + 4g + r
    float csr[4][4];
    f32x4 b2v[4];
    #pragma unroll
    for (int nt = 0; nt < 4; ++nt) {
        #pragma unroll
        for (int r = 0; r < 4; ++r) {
            csr[nt][r]  = __shfl(cs_col[nt], 4*g + r);   // lane 4g+r (grp 0) holds j=nt*16+4g+r
            b2v[nt][r]  = b2[nt*16 + 4*g + r];
        }
    }
    // W3 A-fragments for the 2nd-level MFMA: rows = channel (col<3), K = j
    half8v A3[2];
    #pragma unroll
    for (int kp = 0; kp < 2; ++kp) {
        #pragma unroll
        for (int e = 0; e < 8; ++e) {
            const int j = kp*32 + 4*g + (e & 3) + 16*(e >> 2);
            A3[kp][e] = (col < 3) ? (_Float16)W3[j*3 + col] : (_Float16)0.0f;
        }
    }
    const float b3c0 = b3[0], b3c1 = b3[1], b3c2 = b3[2];

    // ---------------- per-sample state (sample = col, replicated x4 groups) ----------------
    const int idx = blockIdx.x*64 + (tid >> 6)*16 + col;
    const float x0v = xin[idx*3 + 0], x1v = xin[idx*3 + 1], x2v = xin[idx*3 + 2];
    const float t0  = tin[idx];

    float z0 = x0v, z1 = x1v, z2 = x2v;
    float dacc = 0.0f;
    const float hstep = 0.25f;
    float kz0 = 0.f, kz1 = 0.f, kz2 = 0.f;
    float sa0 = 0.f, sa1 = 0.f, sa2 = 0.f;

    #pragma unroll 1
    for (int it = 0; it < 16; ++it) {
        const int st   = it & 3;
        const int step = it >> 2;
        const float alpha = (st == 0) ? 0.0f : ((st == 3) ? hstep : 0.5f * hstep);
        const float wgt   = (st == 1 || st == 2) ? (hstep * (1.0f/3.0f)) : (hstep * (1.0f/6.0f));
        const float s     = (float)step * hstep + alpha;
        const float zi0 = fmaf(alpha, kz0, z0);
        const float zi1 = fmaf(alpha, kz1, z1);
        const float zi2 = fmaf(alpha, kz2, z2);
        const float tt  = t0 * (1.0f - s);

        // ---- layer 1 -> B-fragments (h and h^2), same k-map ----
        half8v BH[2], BQ[2];
        #pragma unroll
        for (int kh = 0; kh < 2; ++kh) {
            #pragma unroll
            for (int e = 0; e < 8; ++e) {
                const int k = kh*32 + 4*g + (e & 3) + 16*(e >> 2);
                const float4 w = sW1[k];
                const float pre = fmaf(zi0, w.x, fmaf(zi1, w.y, fmaf(zi2, w.z,
                                  fmaf(tt, w.w, sb1[k]))));
                BH[kh][e] = (_Float16)fast_tanh(pre);
            }
            BQ[kh] = BH[kh] * BH[kh];   // packed f16 mul
        }

        // ---- layer 2 + divergence bilinear: D[j, sample] ----
        f32x4 a2[4], d2[4];
        #pragma unroll
        for (int nt = 0; nt < 4; ++nt) {
            f32x4 acc = b2v[nt];
            acc = __builtin_amdgcn_mfma_f32_16x16x32_f16(AW2[nt*2+0], BH[0], acc, 0, 0, 0);
            acc = __builtin_amdgcn_mfma_f32_16x16x32_f16(AW2[nt*2+1], BH[1], acc, 0, 0, 0);
            a2[nt] = acc;
            f32x4 z4; z4[0]=0.f; z4[1]=0.f; z4[2]=0.f; z4[3]=0.f;
            z4  = __builtin_amdgcn_mfma_f32_16x16x32_f16(AHW[nt*2+0], BQ[0], z4, 0, 0, 0);
            z4  = __builtin_amdgcn_mfma_f32_16x16x32_f16(AHW[nt*2+1], BQ[1], z4, 0, 0, 0);
            d2[nt] = z4;
        }

        // ---- epilogue: per-lane j-slice (j = nt*16 + 4g + r), sample = col ----
        float h2v[4][4];
        float pdv = 0.0f;
        #pragma unroll
        for (int nt = 0; nt < 4; ++nt) {
            #pragma unroll
            for (int r = 0; r < 4; ++r) {
                const float h2 = fast_tanh(a2[nt][r]);
                h2v[nt][r] = h2;
                const float s2 = fmaf(-h2, h2, 1.0f);
                pdv = fmaf(s2, csr[nt][r] - d2[nt][r], pdv);
            }
        }
        // f = h2 @ W3 via 2nd-level MFMA: tanh(D1) is directly a K=j B-frag
        half8v B2h[2];
        #pragma unroll
        for (int kp = 0; kp < 2; ++kp) {
            #pragma unroll
            for (int e = 0; e < 8; ++e) {
                B2h[kp][e] = (_Float16)h2v[kp*2 + (e >> 2)][e & 3];
            }
        }
        f32x4 fD; fD[0]=0.f; fD[1]=0.f; fD[2]=0.f; fD[3]=0.f;
        fD = __builtin_amdgcn_mfma_f32_16x16x32_f16(A3[0], B2h[0], fD, 0, 0, 0);
        fD = __builtin_amdgcn_mfma_f32_16x16x32_f16(A3[1], B2h[1], fD, 0, 0, 0);

        // dv: sum over 4 groups; f: rows 0..2 live in group-0 lanes
        pdv += __shfl_xor(pdv, 16);
        pdv += __shfl_xor(pdv, 32);
        const float f0 = __shfl(fD[0], col) + b3c0;
        const float f1 = __shfl(fD[1], col) + b3c1;
        const float f2 = __shfl(fD[2], col) + b3c2;

        // ---- RK4 stage update (sample = col, replicated across groups) ----
        const float v0 = -t0 * f0, v1 = -t0 * f1, v2 = -t0 * f2;
        const float vd =  t0 * pdv;
        kz0 = v0; kz1 = v1; kz2 = v2;
        dacc = fmaf(wgt, vd, dacc);
        if (st == 0) { sa0 = wgt*v0; sa1 = wgt*v1; sa2 = wgt*v2; }
        else         { sa0 = fmaf(wgt, v0, sa0); sa1 = fmaf(wgt, v1, sa1); sa2 = fmaf(wgt, v2, sa2); }
        if (st == 3) { z0 += sa0; z1 += sa1; z2 += sa2; }
    }

    // ---------------- mask, grid-sample, store (group 0 only) ----------------
    if (g == 0) {
        const bool m = (t0 > 0.0f);
        const float q0 = m ? z0 : x0v;
        const float q1 = m ? z1 : x1v;
        const float q2 = m ? z2 : x2v;
        const float dfin = m ? dacc : 0.0f;

        const float px = ((q0 * 0.2f + 1.0f) * 100.0f - 1.0f) * 0.5f;
        const float py = ((q1 * 0.2f + 1.0f) * 100.0f - 1.0f) * 0.5f;
        const float pz = ((q2 * 0.2f + 1.0f) * 100.0f - 1.0f) * 0.5f;
        const float fx = floorf(px), fy = floorf(py), fz = floorf(pz);
        const int ix0 = (int)fx, iy0 = (int)fy, iz0 = (int)fz;
        const float wx1 = px - fx, wy1 = py - fy, wz1 = pz - fz;

        float gs = 0.0f;
        #pragma unroll
        for (int c = 0; c < 8; ++c) {
            const int dxc = c & 1, dyc = (c >> 1) & 1, dzc = (c >> 2) & 1;
            const int ix = ix0 + dxc, iy = iy0 + dyc, iz = iz0 + dzc;
            const float w = (dxc ? wx1 : 1.0f - wx1)
                          * (dyc ? wy1 : 1.0f - wy1)
                          * (dzc ? wz1 : 1.0f - wz1);
            if (ix >= 0 && ix < 100 && iy >= 0 && iy < 100 && iz >= 0 && iz < 100)
                gs += vol[(iz * 100 + iy) * 100 + ix] * w;
        }
        out[idx] = gs - dfin;
    }
}

extern "C" void kernel_launch(void* const* d_in, const int* in_sizes, int n_in,
                              void* d_out, int out_size, void* d_ws, size_t ws_size,
                              hipStream_t stream) {
    const float* x    = (const float*)d_in[0];
    const float* t    = (const float*)d_in[1];
    const float* W1   = (const float*)d_in[2];
    const float* b1   = (const float*)d_in[3];
    const float* W2   = (const float*)d_in[4];
    const float* b2   = (const float*)d_in[5];
    const float* W3   = (const float*)d_in[6];
    const float* b3   = (const float*)d_in[7];
    const float* vol  = (const float*)d_in[8];
    float* out = (float*)d_out;

    dim3 grid(NSAMP / 64), block(256);   // 4 waves/block, 16 samples/wave
    cnf_logp_kernel<<<grid, block, 0, stream>>>(x, t, W1, b1, W2, b2, W3, b3, vol, out);
}